// Round 1
// baseline (67.069 us; speedup 1.0000x reference)
//
#include <hip/hip_runtime.h>
#include <math.h>

// Hyp_plus_MLR closed form (all reductions along a_hat = z_k/||z_k||):
//   ts=sign(r)tanh(|r|*||z||), an=||z||/cosh^2 r, w=(y.z)/||z||
//   xy=-ts*w, x2=ts^2, A=1+2xy+y2, Bc=1-x2, den=1+2xy+x2*y2
//   P=A^2 x2+2ABc xy+Bc^2 y2, |m|^2=P/den^2, ma=(Bc w-A ts)/den
//   ma*lam = 2(Bc w-A ts)*den/(den^2-P)
//   out[b,k] = an2 * asinh(ma*lam),  an2 = 2||z||/cosh^2 r
//
// R7 -> R8:
//  * d-quarter q moved from wave index to lane index (lane = q*16+kk):
//    partial reduction over q is 2x shfl_xor(16,32) instead of the
//    part4 LDS round-trip (whose gather was a 16-way bank conflict).
//    Export once to red[h][r][k] (stride-1 in k: conflict-free both sides).
//    y loads become per-lane vector loads (vmcnt) -> no lgkmcnt(0)
//    conflation with z ds_reads.
//  * per-k transcendentals (tanh/cosh/sqrt/rcp) hoisted to a 128-thread
//    phase (1x per block instead of 8x per element): 8x fewer bundles.
//  * light per-element epilogue: ~25 ops, single rcp+NR, asinh via
//    sign(v)*ln(|v|+sqrt(v^2+1)) with __logf; den^2-P via one fma
//    (better conditioned than 1-mm).
//  * R staged to LDS in phase 0 (no late cold-HBM stall).

#define D_DIM 256
#define K_DIM 128
#define ZS    260   // z row stride (floats): keeps b128 reads at min cycles
#define ROWS  8

__global__ __launch_bounds__(1024) void hyp_mlr_kernel(
    const float* __restrict__ Y,   // (2048,256)
    const float* __restrict__ Z,   // (128,256)
    const float* __restrict__ R,   // (128,1)
    float* __restrict__ out)       // (2048,128)
{
  __shared__ float zt[K_DIM * ZS];       // 133,120 B: full Z, padded rows
  __shared__ float red[2][4][K_DIM];     //   4,096 B: dots [h][r][k], stride-1 k
  __shared__ float nzf[K_DIM];           //     512 B: ||z_k||^2
  __shared__ float sy2[ROWS];            //      32 B
  __shared__ float rld[K_DIM];           //     512 B: staged R
  __shared__ float pk_ts[K_DIM], pk_x2[K_DIM], pk_bc[K_DIM],
                   pk_in[K_DIM], pk_a2[K_DIM];   // 2,560 B per-k tables

  const int t    = threadIdx.x;
  const int lane = t & 63;
  const int wv   = __builtin_amdgcn_readfirstlane(threadIdx.x >> 6); // 0..15
  const int kk   = lane & 15;            // k within group
  const int q    = lane >> 4;            // d-quarter, per-lane now
  const int kg   = wv & 7;               // k-group (uniform)
  const int h    = wv >> 3;              // row-half (uniform)
  const int k    = kg * 16 + kk;         // 0..127
  const int b0   = blockIdx.x * ROWS;
  const float* __restrict__ yb = Y + (size_t)b0 * D_DIM;

  // ---- phase 0: stage Z -> LDS (coalesced), R -> LDS, y2 ----
  #pragma unroll
  for (int i = 0; i < 8; ++i) {
    int idx = t + i * 1024;
    int r = idx >> 6, c = idx & 63;
    float4 v = *(const float4*)(Z + r * D_DIM + c * 4);
    *(float4*)&zt[r * ZS + c * 4] = v;
  }
  if (t < K_DIM) rld[t] = R[t];

  if (wv < ROWS) {                       // y2: wave wv owns row wv
    const float* yr = yb + wv * D_DIM;
    float4 u = *(const float4*)(yr + lane * 4);
    float s = u.x*u.x + u.y*u.y + u.z*u.z + u.w*u.w;
    #pragma unroll
    for (int off = 32; off > 0; off >>= 1) s += __shfl_xor(s, off);
    if (lane == 0) sy2[wv] = s;
  }

  __syncthreads();

  // ---- main: per lane (k, q): 4 rows x 64 d, two 32-float sub-chunks ----
  float acc[4] = {0.f, 0.f, 0.f, 0.f};
  float nzp = 0.f;
  const float* zp = &zt[k * ZS + q * 64];
  const float* yq = yb + (size_t)h * 4 * D_DIM + q * 64;
  #pragma unroll
  for (int sub = 0; sub < 2; ++sub) {
    float4 zr[8];
    #pragma unroll
    for (int i = 0; i < 8; ++i) zr[i] = *(const float4*)(zp + sub * 32 + 4 * i);
    #pragma unroll
    for (int i = 0; i < 8; ++i) {
      nzp = fmaf(zr[i].x, zr[i].x, nzp); nzp = fmaf(zr[i].y, zr[i].y, nzp);
      nzp = fmaf(zr[i].z, zr[i].z, nzp); nzp = fmaf(zr[i].w, zr[i].w, nzp);
    }
    #pragma unroll
    for (int r = 0; r < 4; ++r) {
      const float* yr = yq + r * D_DIM + sub * 32;
      float a = acc[r];
      #pragma unroll
      for (int i = 0; i < 8; ++i) {
        float4 yv = *(const float4*)(yr + 4 * i);  // per-lane vector load
        a = fmaf(yv.x, zr[i].x, a);
        a = fmaf(yv.y, zr[i].y, a);
        a = fmaf(yv.z, zr[i].z, a);
        a = fmaf(yv.w, zr[i].w, a);
      }
      acc[r] = a;
    }
  }

  // ---- reduce over q in-wave (lanes ^16, ^32), export conflict-free ----
  #pragma unroll
  for (int r = 0; r < 4; ++r) {
    acc[r] += __shfl_xor(acc[r], 16);
    acc[r] += __shfl_xor(acc[r], 32);
  }
  nzp += __shfl_xor(nzp, 16);
  nzp += __shfl_xor(nzp, 32);

  if (q == 0) {
    #pragma unroll
    for (int r = 0; r < 4; ++r) red[h][r][k] = acc[r];  // bank = k mod 32
    if (h == 0) nzf[k] = nzp;
  }

  __syncthreads();

  // ---- per-k hoist: transcendentals once per k (2 waves) ----
  if (t < K_DIM) {
    const int ke = t;
    float nz2 = nzf[ke];
    float rv  = rld[ke];
    float nz  = sqrtf(nz2);
    float un  = fmaxf(fabsf(rv) * nz, 1e-15f);     // EPS clamp, matches ref
    float ts  = copysignf(tanhf(un), rv);
    float ch  = coshf(rv);
    float x2  = ts * ts;
    pk_ts[ke] = ts;
    pk_x2[ke] = x2;
    pk_bc[ke] = 1.f - x2;
    pk_in[ke] = 1.f / fmaxf(nz, 1e-30f);
    pk_a2[ke] = 2.f * nz / (ch * ch);
  }

  __syncthreads();

  // ---- flat light epilogue: thread -> one (row, k) element ----
  {
    const int ke  = t & 127;
    const int row = t >> 7;                        // 0..7 (wave-uniform)
    float a   = red[row >> 2][row & 3][ke];        // stride-1: conflict-free
    float y2  = sy2[row];                          // broadcast
    float ts  = pk_ts[ke];
    float x2  = pk_x2[ke];
    float Bc  = pk_bc[ke];
    float w   = a * pk_in[ke];                     // y . a_hat
    float xy  = -ts * w;
    float s   = fmaf(2.f, xy, 1.f);                // 1 + 2xy
    float A   = s + y2;
    float den = fmaf(x2, y2, s);
    float P   = fmaf(A, fmaf(x2, A, 2.f * Bc * xy), Bc * Bc * y2);
    float d   = fmaf(den, den, -P);                // den^2 - P  (= den^2(1-mm))
    float qn  = 2.f * fmaf(Bc, w, -(A * ts)) * den;
    float r0  = __builtin_amdgcn_rcpf(d);
    r0 = r0 * (2.f - d * r0);                      // 1 NR step -> ~IEEE quality
    float v   = qn * r0;                           // ma * lam
    float sv  = fabsf(v);
    float t2  = sqrtf(fmaf(sv, sv, 1.f));
    float res = pk_a2[ke] * __logf(sv + t2);       // an2 * asinh(|v|)
    out[(size_t)(b0 + row) * K_DIM + ke] = copysignf(res, v);
  }
}

extern "C" void kernel_launch(void* const* d_in, const int* in_sizes, int n_in,
                              void* d_out, int out_size, void* d_ws, size_t ws_size,
                              hipStream_t stream) {
  const float* Y = (const float*)d_in[0];
  const float* Z = (const float*)d_in[1];
  const float* R = (const float*)d_in[2];
  float* out = (float*)d_out;
  hipLaunchKernelGGL(hyp_mlr_kernel, dim3(2048 / ROWS), dim3(1024), 0, stream,
                     Y, Z, R, out);
}

// Round 2
// 66.045 us; speedup vs baseline: 1.0155x; 1.0155x over previous
//
#include <hip/hip_runtime.h>
#include <math.h>

// Hyp_plus_MLR closed form (all reductions along a_hat = z_k/||z_k||):
//   ts=sign(r)tanh(|r|*||z||), an2=2||z||/cosh^2 r, w=(y.z)/||z||
//   xy=-ts*w, x2=ts^2, A=1+2xy+y2, Bc=1-x2, den=1+2xy+x2*y2
//   P=A^2 x2+2ABc xy+Bc^2 y2, ma*lam = 2(Bc w-A ts)*den/(den^2-P)
//   out[b,k] = an2 * asinh(ma*lam)
//
// R8 -> R9 (post-mortem: epilogue was ~0.5us, not the bottleneck; kernel
// is latency-bound at 1 block/CU with barrier-serialized phases):
//  * k-split across blocks: each block stages HALF of Z (64 rows, 66.5 KB
//    LDS) and computes 16 y-rows x 64 k. Grid stays 256, but LDS < 80 KB
//    -> 2 blocks/CU = 8 waves/SIMD (was 4): one block's main loop overlaps
//    the other's staging latency and barriers. __launch_bounds__(1024,8)
//    caps VGPR at 64 to guarantee it.
//  * main loop restored to R7's proven shape: z from LDS in regs,
//    y via WAVE-UNIFORM scalar loads (s_load pipe, no vmcnt conflation) --
//    R8's per-lane y vector loads were the regression.
//  * partial-export buffers alias the dead zt region (barrier-protected):
//    stride-1 in k on both sides, conflict-free, no extra LDS.
//  * epilogue keeps R8's cheap math (exp-based tanh/sech^2, fused rcp+NR,
//    asinh via __logf) computed inline per element (no extra barrier).

#define D_DIM 256
#define K_DIM 128
#define KB    64    // k-columns per block (half of Z)
#define ZS    260   // z row stride (floats): same bank pattern as R7, proven
#define ROWS  16

__global__ __launch_bounds__(1024, 8) void hyp_mlr_kernel(
    const float* __restrict__ Y,   // (2048,256)
    const float* __restrict__ Z,   // (128,256)
    const float* __restrict__ R,   // (128,1)
    float* __restrict__ out)       // (2048,128)
{
  __shared__ float zt[KB * ZS];    // 66,560 B; dead after main loop -> aliased
  __shared__ float sy2[ROWS];      // y2 per row
  __shared__ float rld[KB];        // staged R for this k-half

  const int t    = threadIdx.x;
  const int lane = t & 63;
  const int wv   = __builtin_amdgcn_readfirstlane(threadIdx.x >> 6); // 0..15
  const int dq   = wv & 3;               // d-quarter (wave-uniform)
  const int rg   = wv >> 2;              // row-group, 4 rows each (uniform)
  const int blk  = blockIdx.x;
  const int b0   = (blk >> 1) * ROWS;    // first y-row
  const int kh   = blk & 1;              // k-half
  const float* __restrict__ yb   = Y + (size_t)b0 * D_DIM;
  const float* __restrict__ zsrc = Z + (size_t)kh * KB * D_DIM;

  // ---- phase 0: stage half-Z -> LDS (coalesced), R -> LDS, y2 ----
  #pragma unroll
  for (int i = 0; i < 4; ++i) {
    int idx = t + i * 1024;              // 4096 float4 = 64 KB
    int r = idx >> 6, c = idx & 63;
    float4 v = *(const float4*)(zsrc + r * D_DIM + c * 4);
    *(float4*)&zt[r * ZS + c * 4] = v;
  }
  if (t < KB) rld[t] = R[kh * KB + t];

  {                                      // y2: wave wv owns row wv (16=16)
    const float* yr = yb + wv * D_DIM;
    float4 u = *(const float4*)(yr + lane * 4);
    float s = u.x*u.x + u.y*u.y + u.z*u.z + u.w*u.w;
    #pragma unroll
    for (int off = 32; off > 0; off >>= 1) s += __shfl_xor(s, off);
    if (lane == 0) sy2[wv] = s;
  }

  __syncthreads();

  // ---- main: lane = k (0..63), wave-uniform (dq, rg): 4 rows x 64 d ----
  float acc[4] = {0.f, 0.f, 0.f, 0.f};
  float nzp = 0.f;
  const float* zp = &zt[lane * ZS + dq * 64];
  const float* yq = yb + (size_t)rg * 4 * D_DIM + dq * 64;  // wave-uniform
  #pragma unroll
  for (int sub = 0; sub < 2; ++sub) {
    float4 zr[8];
    #pragma unroll
    for (int i = 0; i < 8; ++i) zr[i] = *(const float4*)(zp + sub * 32 + 4 * i);
    if (rg == 0) {                       // nz2 only needed once per (k,dq)
      #pragma unroll
      for (int i = 0; i < 8; ++i) {
        nzp = fmaf(zr[i].x, zr[i].x, nzp); nzp = fmaf(zr[i].y, zr[i].y, nzp);
        nzp = fmaf(zr[i].z, zr[i].z, nzp); nzp = fmaf(zr[i].w, zr[i].w, nzp);
      }
    }
    #pragma unroll
    for (int r = 0; r < 4; ++r) {
      const float* yr = yq + r * D_DIM + sub * 32;
      float a = acc[r];
      #pragma unroll
      for (int i = 0; i < 8; ++i) {
        float4 yv = *(const float4*)(yr + 4 * i);   // uniform -> scalar cache
        a = fmaf(yv.x, zr[i].x, a);
        a = fmaf(yv.y, zr[i].y, a);
        a = fmaf(yv.z, zr[i].z, a);
        a = fmaf(yv.w, zr[i].w, a);
      }
      acc[r] = a;
    }
  }

  __syncthreads();   // zt reads complete everywhere -> safe to alias

  // ---- export partials into the dead zt region, stride-1 in k ----
  float* red = zt;                        // [ (dq*ROWS + row) * KB + k ]
  float* nzq = zt + 4 * ROWS * KB;        // [ dq*KB + k ]
  #pragma unroll
  for (int r = 0; r < 4; ++r)
    red[(dq * ROWS + rg * 4 + r) * KB + lane] = acc[r];   // conflict-free
  if (rg == 0) nzq[dq * KB + lane] = nzp;

  __syncthreads();

  // ---- flat epilogue: thread -> one (row, k) element ----
  {
    const int ke  = t & 63;
    const int row = t >> 6;               // 0..15 (wave-uniform)
    float a = 0.f, nz2 = 0.f;
    #pragma unroll
    for (int q2 = 0; q2 < 4; ++q2) {
      a   += red[(q2 * ROWS + row) * KB + ke];   // stride-1: conflict-free
      nz2 += nzq[q2 * KB + ke];
    }
    float rv = rld[ke];
    float y2 = sy2[row];                  // wave-uniform broadcast
    float nz = sqrtf(nz2);
    float ar = fabsf(rv);
    float un = fmaxf(ar * nz, 1e-15f);    // EPS clamp, matches ref
    // tanh(un) = 1 - 2e/(1+e), e = exp(-2un)
    float te = __expf(-2.f * un);
    float d1 = 1.f + te;
    float r1 = __builtin_amdgcn_rcpf(d1); r1 = r1 * (2.f - d1 * r1);
    float ts = copysignf(1.f - 2.f * te * r1, rv);
    // sech^2(rv) = 4u/(1+u)^2, u = exp(-2|rv|)
    float ue = __expf(-2.f * ar);
    float d2 = 1.f + ue;
    float r2 = __builtin_amdgcn_rcpf(d2); r2 = r2 * (2.f - d2 * r2);
    float an2 = 2.f * nz * (4.f * ue * r2 * r2);
    float nzc = fmaxf(nz, 1e-30f);
    float ri  = __builtin_amdgcn_rcpf(nzc); ri = ri * (2.f - nzc * ri);
    float x2  = ts * ts;
    float w   = a * ri;                   // y . a_hat
    float xy  = -ts * w;
    float s   = fmaf(2.f, xy, 1.f);       // 1 + 2xy
    float A   = s + y2;
    float Bc  = 1.f - x2;
    float den = fmaf(x2, y2, s);
    float P   = fmaf(A, fmaf(x2, A, 2.f * Bc * xy), Bc * Bc * y2);
    float d   = fmaf(den, den, -P);       // den^2 - P = den^2 (1 - |m|^2)
    float qn  = 2.f * fmaf(Bc, w, -(A * ts)) * den;
    float r0  = __builtin_amdgcn_rcpf(d); r0 = r0 * (2.f - d * r0);
    float v   = qn * r0;                  // ma * lam
    float sv  = fabsf(v);
    float t2  = sqrtf(fmaf(sv, sv, 1.f));
    float res = an2 * __logf(sv + t2);    // an2 * asinh(|v|)
    out[(size_t)(b0 + row) * K_DIM + kh * KB + ke] = copysignf(res, v);
  }
}

extern "C" void kernel_launch(void* const* d_in, const int* in_sizes, int n_in,
                              void* d_out, int out_size, void* d_ws, size_t ws_size,
                              hipStream_t stream) {
  const float* Y = (const float*)d_in[0];
  const float* Z = (const float*)d_in[1];
  const float* R = (const float*)d_in[2];
  float* out = (float*)d_out;
  hipLaunchKernelGGL(hyp_mlr_kernel, dim3((2048 / ROWS) * 2), dim3(1024), 0,
                     stream, Y, Z, R, out);
}